// Round 5
// baseline (107.827 us; speedup 1.0000x reference)
//
#include <hip/hip_runtime.h>
#include <hip/hip_bf16.h>
#include <stdint.h>

typedef __bf16 bf16x8 __attribute__((ext_vector_type(8)));
typedef float  f32x4  __attribute__((ext_vector_type(4)));

// Weights pre-swizzled into MFMA B-fragment order:
//  slot = (ktile * NF + nfrag); value j of lane l = W[ktile*32 + (l>>4)*8 + j][nfrag*16 + (l&15)]
// Layer 1: K=800 (784 + zero pad), N=512 (500 + pad), 25 k-tiles, 32 n-frags
// Layer 2: K=512 (500 + pad), N=256 (200 + pad), 16 k-tiles, 16 n-frags
// Layer 3: K=256 (200 + pad), N=16 (10 + pad),   8 k-tiles,  1 n-frag

#define KT1 25
#define NF1 32
#define KT2 16
#define NF2 16
#define KT3 8

__global__ void prep_w1(const float* __restrict__ W1, const float* __restrict__ cw,
                        __bf16* __restrict__ w1s) {
  int gid  = blockIdx.x * 256 + threadIdx.x;   // 51200 threads
  int lane = gid & 63;
  int slot = gid >> 6;                         // 0..799
  int t = slot >> 5;
  int f = slot & 31;
  int kbase = t * 32 + ((lane >> 4) << 3);
  int n = f * 16 + (lane & 15);
  float c[9];
#pragma unroll
  for (int i = 0; i < 9; ++i) c[i] = cw[i];
  bf16x8 v;
#pragma unroll
  for (int e = 0; e < 8; ++e) {
    int k = kbase + e;
    float acc = 0.f;
    if (k < 784 && n < 500) {
      int pi = k / 28, pj = k % 28;
#pragma unroll
      for (int dr = 0; dr < 3; ++dr) {
        int r = pi - dr;
        if (r < 0 || r >= 26) continue;
#pragma unroll
        for (int dc = 0; dc < 3; ++dc) {
          int cc = pj - dc;
          if (cc < 0 || cc >= 26) continue;
          acc += c[dr * 3 + dc] * W1[(size_t)(r * 26 + cc) * 500 + n];
        }
      }
    }
    v[e] = (__bf16)acc;
  }
  *(bf16x8*)(w1s + (size_t)(slot * 64 + lane) * 8) = v;
}

__global__ void prep_w2(const float* __restrict__ W2, __bf16* __restrict__ w2s) {
  int gid  = blockIdx.x * 256 + threadIdx.x;
  int lane = gid & 63;
  int slot = gid >> 6;
  int t = slot >> 4;
  int f = slot & 15;
  int kbase = t * 32 + ((lane >> 4) << 3);
  int n = f * 16 + (lane & 15);
  bf16x8 v;
#pragma unroll
  for (int e = 0; e < 8; ++e) {
    int k = kbase + e;
    float val = (k < 500 && n < 200) ? W2[(size_t)k * 200 + n] : 0.f;
    v[e] = (__bf16)val;
  }
  *(bf16x8*)(w2s + (size_t)(slot * 64 + lane) * 8) = v;
}

__global__ void prep_w3(const float* __restrict__ W3, __bf16* __restrict__ w3s) {
  int gid  = blockIdx.x * 256 + threadIdx.x;
  int lane = gid & 63;
  int t    = gid >> 6;
  int kbase = t * 32 + ((lane >> 4) << 3);
  int n = lane & 15;
  bf16x8 v;
#pragma unroll
  for (int e = 0; e < 8; ++e) {
    int k = kbase + e;
    float val = (k < 200 && n < 10) ? W3[(size_t)k * 10 + n] : 0.f;
    v[e] = (__bf16)val;
  }
  *(bf16x8*)(w3s + (size_t)(t * 64 + lane) * 8) = v;
}

// ---- fused 3-layer MLP, 64 rows/block, 4 waves ----
// Layer-1 x staged via global_load_lds into a 3-deep ring of 8KB buffers that
// lives in the FIRST 24KB of the h1 buffer (xs dead before h1 written).
// Raw s_barrier + counted vmcnt(2): stage loads stay in flight across barriers.
__global__ __launch_bounds__(256, 2) void mlp_fused(
    const float* __restrict__ x,
    const __bf16* __restrict__ w1s, const __bf16* __restrict__ w2s,
    const __bf16* __restrict__ w3s,
    const float* __restrict__ b1, const float* __restrict__ b2,
    const float* __restrict__ b3,
    float* __restrict__ out)
{
  __shared__ __align__(16) char smem[64 * 1024];   // h1 (64 rows x 512 bf16, swizzled); first 24KB doubles as xs ring
  __shared__ float sb1[512];
  __shared__ float sb2[256];

  const int tid  = threadIdx.x;
  const int lane = tid & 63;
  const int w    = tid >> 6;   // wave 0..3
  const int lrow = lane & 15;
  const int lgrp = lane >> 4;  // 0..3
  const int brow = blockIdx.x * 64;

  sb1[tid]       = (tid < 500) ? b1[tid] : 0.f;
  sb1[tid + 256] = (tid + 256 < 500) ? b1[tid + 256] : 0.f;
  sb2[tid]       = (tid < 200) ? b2[tid] : 0.f;

  const f32x4 FZ = {0.f, 0.f, 0.f, 0.f};

  // ---------------- Layer 1: h1 = relu(x @ W1eff + b1) ----------------
  f32x4 acc1[4][8];
#pragma unroll
  for (int m = 0; m < 4; ++m)
#pragma unroll
    for (int f = 0; f < 8; ++f) acc1[m][f] = FZ;

  const bf16x8* w1p = (const bf16x8*)w1s + ((size_t)(w * 8) * 64 + lane);

  // stage one 64x32 fp32 x-tile (8KB) into ring buffer at byte offset sb.
  // chunk (r,q) at sb + r*128 + q*16 holds x[brow+r][t*32 + (q^(r&7))*4 ..+4)
  auto stage_to = [&](int t, int sbo) {
    int tt = (t > 24) ? 24 : t;
#pragma unroll
    for (int i = 0; i < 2; ++i) {
      int c = i * 256 + tid;
      int r = c >> 3, q = c & 7;
      int gk = tt * 32 + ((q ^ (r & 7)) << 2);
      if (gk > 780) gk = 768;   // tail: garbage hits zero B rows (k>=784)
      const float* gsrc = x + (size_t)(brow + r) * 784 + gk;
      __builtin_amdgcn_global_load_lds(
          (const __attribute__((address_space(1))) void*)gsrc,
          (__attribute__((address_space(3))) void*)(smem + sbo + (size_t)(i * 256 + w * 64) * 16),
          16, 0, 0);
    }
  };

  bf16x8 bA[8], bB[8];

  // per-tile body: issue B(t+1) -> bn, stage(t+2), read A from ring[rb], 32 MFMA w/ bc,
  // end with counted vmcnt(2) (retires s(t+1)+B(t+1), leaves s(t+2) in flight) + barrier.
  auto body1 = [&](int t, bf16x8 (&bc)[8], bf16x8 (&bn)[8], int rb, int sbo) {
#pragma unroll
    for (int f = 0; f < 8; ++f) bn[f] = w1p[(size_t)((t + 1) * NF1 + f) * 64];
    stage_to(t + 2, sbo);

    const char* xb = smem + rb;
    f32x4 u0[4], u1[4];
#pragma unroll
    for (int m = 0; m < 4; ++m) {
      int r = m * 16 + lrow;
      int swz = (r & 7) << 4;
      u0[m] = *(const f32x4*)(xb + r * 128 + ((lgrp * 32) ^ swz));
      u1[m] = *(const f32x4*)(xb + r * 128 + ((lgrp * 32 + 16) ^ swz));
    }
    bf16x8 afr[4];
#pragma unroll
    for (int m = 0; m < 4; ++m) {
      bf16x8 a;
#pragma unroll
      for (int e = 0; e < 4; ++e) { a[e] = (__bf16)u0[m][e]; a[e + 4] = (__bf16)u1[m][e]; }
      afr[m] = a;
    }
#pragma unroll
    for (int f = 0; f < 8; ++f)
#pragma unroll
      for (int m = 0; m < 4; ++m)
        acc1[m][f] = __builtin_amdgcn_mfma_f32_16x16x32_bf16(afr[m], bc[f], acc1[m][f], 0, 0, 0);

    asm volatile("s_waitcnt vmcnt(2)\n\ts_barrier" ::: "memory");
  };

  // prologue: B(0), stage(0)->buf0, stage(1)->buf1; wait s(0) (vmcnt(2)) + sb writes, barrier
#pragma unroll
  for (int f = 0; f < 8; ++f) bA[f] = w1p[(size_t)f * 64];
  stage_to(0, 0);
  stage_to(1, 8192);
  asm volatile("s_waitcnt vmcnt(2) lgkmcnt(0)\n\ts_barrier" ::: "memory");

  // tiles 0..23: 6x-unrolled (LCM of 2 reg-sets x 3 ring-bufs)
  for (int t = 0; t < 24; t += 6) {
    body1(t + 0, bA, bB, 0,     16384);
    body1(t + 1, bB, bA, 8192,  0);
    body1(t + 2, bA, bB, 16384, 8192);
    body1(t + 3, bB, bA, 0,     16384);
    body1(t + 4, bA, bB, 8192,  0);
    body1(t + 5, bB, bA, 16384, 8192);
  }
  // tail tile 24: ring buf 0, reg set A; no new loads
  {
    const char* xb = smem;
    f32x4 u0[4], u1[4];
#pragma unroll
    for (int m = 0; m < 4; ++m) {
      int r = m * 16 + lrow;
      int swz = (r & 7) << 4;
      u0[m] = *(const f32x4*)(xb + r * 128 + ((lgrp * 32) ^ swz));
      u1[m] = *(const f32x4*)(xb + r * 128 + ((lgrp * 32 + 16) ^ swz));
    }
    bf16x8 afr[4];
#pragma unroll
    for (int m = 0; m < 4; ++m) {
      bf16x8 a;
#pragma unroll
      for (int e = 0; e < 4; ++e) { a[e] = (__bf16)u0[m][e]; a[e + 4] = (__bf16)u1[m][e]; }
      afr[m] = a;
    }
#pragma unroll
    for (int f = 0; f < 8; ++f)
#pragma unroll
      for (int m = 0; m < 4; ++m)
        acc1[m][f] = __builtin_amdgcn_mfma_f32_16x16x32_bf16(afr[m], bA[f], acc1[m][f], 0, 0, 0);
  }
  // drain leftover stage(25) before epilogue overwrites the xs region with h1
  asm volatile("s_waitcnt vmcnt(0)\n\ts_barrier" ::: "memory");

  // epilogue 1: bias + relu + cvt -> h1 (XOR-swizzled rows)
#pragma unroll
  for (int m = 0; m < 4; ++m) {
#pragma unroll
    for (int f = 0; f < 8; ++f) {
      int col = w * 128 + f * 16 + lrow;
      float bias = sb1[col];
#pragma unroll
      for (int r = 0; r < 4; ++r) {
        int row = m * 16 + lgrp * 4 + r;
        float v = fmaxf(acc1[m][f][r] + bias, 0.f);
        int off = row * 1024 + ((col * 2) ^ ((row & 7) << 4));
        *(__bf16*)(smem + off) = (__bf16)v;
      }
    }
  }
  __syncthreads();

  // ---------------- Layer 2: h2 = relu(h1 @ W2 + b2) ----------------
  f32x4 acc2[4][4];
#pragma unroll
  for (int m = 0; m < 4; ++m)
#pragma unroll
    for (int f = 0; f < 4; ++f) acc2[m][f] = FZ;

  const bf16x8* w2p = (const bf16x8*)w2s + ((size_t)(w * 4) * 64 + lane);

  bf16x8 b2a[4], b2b[4];
#pragma unroll
  for (int f = 0; f < 4; ++f) b2a[f] = w2p[(size_t)f * 64];

  for (int t = 0; t < KT2; t += 2) {
#pragma unroll
    for (int f = 0; f < 4; ++f) b2b[f] = w2p[(size_t)((t + 1) * NF2 + f) * 64];
    {
      bf16x8 a2[4];
#pragma unroll
      for (int m = 0; m < 4; ++m) {
        int row = m * 16 + lrow;
        int off = row * 1024 + ((t * 64 + lgrp * 16) ^ ((row & 7) << 4));
        a2[m] = *(const bf16x8*)(smem + off);
      }
#pragma unroll
      for (int f = 0; f < 4; ++f)
#pragma unroll
        for (int m = 0; m < 4; ++m)
          acc2[m][f] = __builtin_amdgcn_mfma_f32_16x16x32_bf16(a2[m], b2a[f], acc2[m][f], 0, 0, 0);
    }
#pragma unroll
    for (int f = 0; f < 4; ++f) b2a[f] = w2p[(size_t)((t + 2) * NF2 + f) * 64];
    {
      bf16x8 a2[4];
#pragma unroll
      for (int m = 0; m < 4; ++m) {
        int row = m * 16 + lrow;
        int off = row * 1024 + (((t + 1) * 64 + lgrp * 16) ^ ((row & 7) << 4));
        a2[m] = *(const bf16x8*)(smem + off);
      }
#pragma unroll
      for (int f = 0; f < 4; ++f)
#pragma unroll
        for (int m = 0; m < 4; ++m)
          acc2[m][f] = __builtin_amdgcn_mfma_f32_16x16x32_bf16(a2[m], b2b[f], acc2[m][f], 0, 0, 0);
    }
  }

  __syncthreads();   // all h1 reads done before overwriting with h2

  // epilogue 2 -> h2 in reused LDS (cols >= 200 exact zeros: acc==0, bias==0)
#pragma unroll
  for (int m = 0; m < 4; ++m) {
#pragma unroll
    for (int f = 0; f < 4; ++f) {
      int col = w * 64 + f * 16 + lrow;
      float bias = sb2[col];
#pragma unroll
      for (int r = 0; r < 4; ++r) {
        int row = m * 16 + lgrp * 4 + r;
        float v = fmaxf(acc2[m][f][r] + bias, 0.f);
        int off = row * 512 + ((col * 2) ^ ((row & 7) << 4));
        *(__bf16*)(smem + off) = (__bf16)v;
      }
    }
  }
  __syncthreads();

  // ---------------- Layer 3: out = h2 @ W3 + b3 (wave w owns rows w*16..) ----------------
  {
    f32x4 a3 = FZ;
    const bf16x8* w3p = (const bf16x8*)w3s + lane;
#pragma unroll
    for (int t = 0; t < KT3; ++t) {
      int row = w * 16 + lrow;
      int off = row * 512 + ((t * 64 + lgrp * 16) ^ ((row & 7) << 4));
      bf16x8 a = *(const bf16x8*)(smem + off);
      a3 = __builtin_amdgcn_mfma_f32_16x16x32_bf16(a, w3p[(size_t)t * 64], a3, 0, 0, 0);
    }
    if (lrow < 10) {
      float bias = b3[lrow];
#pragma unroll
      for (int r = 0; r < 4; ++r)
        out[(size_t)(brow + w * 16 + lgrp * 4 + r) * 10 + lrow] = a3[r] + bias;
    }
  }
}

extern "C" void kernel_launch(void* const* d_in, const int* in_sizes, int n_in,
                              void* d_out, int out_size, void* d_ws, size_t ws_size,
                              hipStream_t stream) {
  const float* x  = (const float*)d_in[0];
  const float* cw = (const float*)d_in[1];
  const float* W1 = (const float*)d_in[2];
  const float* b1 = (const float*)d_in[3];
  const float* W2 = (const float*)d_in[4];
  const float* b2 = (const float*)d_in[5];
  const float* W3 = (const float*)d_in[6];
  const float* b3 = (const float*)d_in[7];
  float* out = (float*)d_out;

  __bf16* w1s = (__bf16*)d_ws;                      // 800 KB
  __bf16* w2s = w1s + (size_t)KT1 * NF1 * 64 * 8;   // 256 KB
  __bf16* w3s = w2s + (size_t)KT2 * NF2 * 64 * 8;   // 8 KB

  prep_w1<<<200, 256, 0, stream>>>(W1, cw, w1s);
  prep_w2<<<64, 256, 0, stream>>>(W2, w2s);
  prep_w3<<<2, 256, 0, stream>>>(W3, w3s);

  mlp_fused<<<65536 / 64, 256, 0, stream>>>(x, w1s, w2s, w3s, b1, b2, b3, out);
}

// Round 6
// 93.037 us; speedup vs baseline: 1.1590x; 1.1590x over previous
//
#include <hip/hip_runtime.h>
#include <hip/hip_bf16.h>
#include <stdint.h>

typedef __bf16 bf16x8 __attribute__((ext_vector_type(8)));
typedef float  f32x4  __attribute__((ext_vector_type(4)));

// Weights pre-swizzled into MFMA B-fragment order:
//  slot = (ktile * NF + nfrag); value j of lane l = W[ktile*32 + (l>>4)*8 + j][nfrag*16 + (l&15)]
// Layer 1: K=800 (784 + zero pad), N=512 (500 + pad), 25 k-tiles, 32 n-frags
// Layer 2: K=512 (500 + pad), N=256 (200 + pad), 16 k-tiles, 16 n-frags
// Layer 3: K=256 (200 + pad), N=16 (10 + pad),   8 k-tiles,  1 n-frag

#define KT1 25
#define NF1 32
#define KT2 16
#define NF2 16
#define KT3 8

__global__ void prep_w1(const float* __restrict__ W1, const float* __restrict__ cw,
                        __bf16* __restrict__ w1s) {
  int gid  = blockIdx.x * 256 + threadIdx.x;   // 51200 threads
  int lane = gid & 63;
  int slot = gid >> 6;                         // 0..799
  int t = slot >> 5;
  int f = slot & 31;
  int kbase = t * 32 + ((lane >> 4) << 3);
  int n = f * 16 + (lane & 15);
  float c[9];
#pragma unroll
  for (int i = 0; i < 9; ++i) c[i] = cw[i];
  bf16x8 v;
#pragma unroll
  for (int e = 0; e < 8; ++e) {
    int k = kbase + e;
    float acc = 0.f;
    if (k < 784 && n < 500) {
      int pi = k / 28, pj = k % 28;
#pragma unroll
      for (int dr = 0; dr < 3; ++dr) {
        int r = pi - dr;
        if (r < 0 || r >= 26) continue;
#pragma unroll
        for (int dc = 0; dc < 3; ++dc) {
          int cc = pj - dc;
          if (cc < 0 || cc >= 26) continue;
          acc += c[dr * 3 + dc] * W1[(size_t)(r * 26 + cc) * 500 + n];
        }
      }
    }
    v[e] = (__bf16)acc;
  }
  *(bf16x8*)(w1s + (size_t)(slot * 64 + lane) * 8) = v;
}

__global__ void prep_w2(const float* __restrict__ W2, __bf16* __restrict__ w2s) {
  int gid  = blockIdx.x * 256 + threadIdx.x;
  int lane = gid & 63;
  int slot = gid >> 6;
  int t = slot >> 4;
  int f = slot & 15;
  int kbase = t * 32 + ((lane >> 4) << 3);
  int n = f * 16 + (lane & 15);
  bf16x8 v;
#pragma unroll
  for (int e = 0; e < 8; ++e) {
    int k = kbase + e;
    float val = (k < 500 && n < 200) ? W2[(size_t)k * 200 + n] : 0.f;
    v[e] = (__bf16)val;
  }
  *(bf16x8*)(w2s + (size_t)(slot * 64 + lane) * 8) = v;
}

__global__ void prep_w3(const float* __restrict__ W3, __bf16* __restrict__ w3s) {
  int gid  = blockIdx.x * 256 + threadIdx.x;
  int lane = gid & 63;
  int t    = gid >> 6;
  int kbase = t * 32 + ((lane >> 4) << 3);
  int n = lane & 15;
  bf16x8 v;
#pragma unroll
  for (int e = 0; e < 8; ++e) {
    int k = kbase + e;
    float val = (k < 200 && n < 10) ? W3[(size_t)k * 10 + n] : 0.f;
    v[e] = (__bf16)val;
  }
  *(bf16x8*)(w3s + (size_t)(t * 64 + lane) * 8) = v;
}

// ---- fused 3-layer MLP, 64 rows/block, 4 waves ----
// Layer-1 x staged via REGISTERS as bf16 (T14): global->reg fp32 (2-tile distance),
// cvt once per element per block, ds_write bf16 into 2x4KB double buffer.
// One raw s_barrier + lgkmcnt(0) per tile; vmem loads stay in flight across it.
// xs layout: row-major [64 rows][32 k] bf16, 16B chunk (row,q) at row*64 + ((q^(row&3))<<4)
// (same involution on write and read -> conflict-free-ish, 2-way max).
__global__ __launch_bounds__(256, 2) void mlp_fused(
    const float* __restrict__ x,
    const __bf16* __restrict__ w1s, const __bf16* __restrict__ w2s,
    const __bf16* __restrict__ w3s,
    const float* __restrict__ b1, const float* __restrict__ b2,
    const float* __restrict__ b3,
    float* __restrict__ out)
{
  __shared__ __align__(16) char xsm[2 * 4096];     // bf16 x-tile double buffer
  __shared__ __align__(16) char h1[64 * 1024];     // h1 (64 x 512 bf16, swizzled); reused for h2
  __shared__ float sb1[512];
  __shared__ float sb2[256];

  const int tid  = threadIdx.x;
  const int lane = tid & 63;
  const int w    = tid >> 6;   // wave 0..3
  const int lrow = lane & 15;
  const int lgrp = lane >> 4;  // 0..3 (quarter)
  const int brow = blockIdx.x * 64;
  const int xr   = tid >> 2;   // staging row 0..63
  const int xq   = tid & 3;    // staging quarter 0..3

  sb1[tid]       = (tid < 500) ? b1[tid] : 0.f;
  sb1[tid + 256] = (tid + 256 < 500) ? b1[tid + 256] : 0.f;
  sb2[tid]       = (tid < 200) ? b2[tid] : 0.f;

  const f32x4 FZ = {0.f, 0.f, 0.f, 0.f};

  // ---------------- Layer 1: h1 = relu(x @ W1eff + b1) ----------------
  f32x4 acc1[4][8];
#pragma unroll
  for (int m = 0; m < 4; ++m)
#pragma unroll
    for (int f = 0; f < 8; ++f) acc1[m][f] = FZ;

  const bf16x8* w1p   = (const bf16x8*)w1s + ((size_t)(w * 8) * 64 + lane);
  const float*  xbase = x + (size_t)(brow + xr) * 784;
  const int     xswz  = (xq ^ (xr & 3)) << 4;      // staging write swizzle
  const int     xoff  = xr * 64 + xswz;            // byte offset within buffer

  // per-thread global load of 8 floats for tile t (clamped tail)
  auto gload = [&](int t, f32x4 (&g)[2]) {
    int gk = t * 32 + xq * 8;
    if (gk > 776) gk = 776;     // k>=784 garbage multiplies zero B rows
    const float* p = xbase + gk;
    g[0] = *(const f32x4*)p;
    g[1] = *(const f32x4*)(p + 4);
  };
  // cvt 8 fp32 -> bf16x8, ds_write into buffer bw
  auto cwrite = [&](f32x4 (&g)[2], int bw) {
    bf16x8 v;
#pragma unroll
    for (int e = 0; e < 4; ++e) { v[e] = (__bf16)g[0][e]; v[e + 4] = (__bf16)g[1][e]; }
    *(bf16x8*)(xsm + bw + xoff) = v;
  };

  f32x4  grA[2], grB[2];
  bf16x8 bA[8], bB[8];

  // body(t): read A(t) from bufR, issue B(t+1)->bn, issue x(t+2)->gl,
  // cvt gc (=x(t+1)) -> write bufW, 32 MFMA with bc, lgkm-only barrier.
  auto body1 = [&](int t, bf16x8 (&bc)[8], bf16x8 (&bn)[8],
                   f32x4 (&gc)[2], f32x4 (&gl)[2], int bufR, int bufW) {
    bf16x8 afr[4];
#pragma unroll
    for (int m = 0; m < 4; ++m) {
      int r = m * 16 + lrow;
      afr[m] = *(const bf16x8*)(xsm + bufR + r * 64 + ((lgrp ^ (r & 3)) << 4));
    }
#pragma unroll
    for (int f = 0; f < 8; ++f) bn[f] = w1p[(size_t)((t + 1) * NF1 + f) * 64];
    gload(t + 2 > 24 ? 24 : t + 2, gl);
    cwrite(gc, bufW);

    __builtin_amdgcn_s_setprio(1);
#pragma unroll
    for (int f = 0; f < 8; ++f)
#pragma unroll
      for (int m = 0; m < 4; ++m)
        acc1[m][f] = __builtin_amdgcn_mfma_f32_16x16x32_bf16(afr[m], bc[f], acc1[m][f], 0, 0, 0);
    __builtin_amdgcn_s_setprio(0);

    asm volatile("s_waitcnt lgkmcnt(0)\n\ts_barrier" ::: "memory");
  };

  // prologue: x(0)->grA, B(0)->bA, x(1)->grB; cvt grA -> buf0; barrier (vmem stays in flight)
  gload(0, grA);
#pragma unroll
  for (int f = 0; f < 8; ++f) bA[f] = w1p[(size_t)f * 64];
  gload(1, grB);
  cwrite(grA, 0);
  asm volatile("s_waitcnt lgkmcnt(0)\n\ts_barrier" ::: "memory");

  // tiles 0..23 (2x unrolled: B-sets, gr-sets, buffers all period-2)
  for (int t = 0; t < 24; t += 2) {
    body1(t,     bA, bB, grB, grA, 0,    4096);
    body1(t + 1, bB, bA, grA, grB, 4096, 0);
  }
  // tail tile 24: read buf0, MFMA with bA; no staging
  {
    bf16x8 afr[4];
#pragma unroll
    for (int m = 0; m < 4; ++m) {
      int r = m * 16 + lrow;
      afr[m] = *(const bf16x8*)(xsm + r * 64 + ((lgrp ^ (r & 3)) << 4));
    }
    __builtin_amdgcn_s_setprio(1);
#pragma unroll
    for (int f = 0; f < 8; ++f)
#pragma unroll
      for (int m = 0; m < 4; ++m)
        acc1[m][f] = __builtin_amdgcn_mfma_f32_16x16x32_bf16(afr[m], bA[f], acc1[m][f], 0, 0, 0);
    __builtin_amdgcn_s_setprio(0);
  }

  // epilogue 1: bias + relu + cvt -> h1 (XOR-swizzled rows)
#pragma unroll
  for (int m = 0; m < 4; ++m) {
#pragma unroll
    for (int f = 0; f < 8; ++f) {
      int col = w * 128 + f * 16 + lrow;
      float bias = sb1[col];
#pragma unroll
      for (int r = 0; r < 4; ++r) {
        int row = m * 16 + lgrp * 4 + r;
        float v = fmaxf(acc1[m][f][r] + bias, 0.f);
        int off = row * 1024 + ((col * 2) ^ ((row & 7) << 4));
        *(__bf16*)(h1 + off) = (__bf16)v;
      }
    }
  }
  __syncthreads();

  // ---------------- Layer 2: h2 = relu(h1 @ W2 + b2) ----------------
  f32x4 acc2[4][4];
#pragma unroll
  for (int m = 0; m < 4; ++m)
#pragma unroll
    for (int f = 0; f < 4; ++f) acc2[m][f] = FZ;

  const bf16x8* w2p = (const bf16x8*)w2s + ((size_t)(w * 4) * 64 + lane);

  bf16x8 b2a[4], b2b[4];
#pragma unroll
  for (int f = 0; f < 4; ++f) b2a[f] = w2p[(size_t)f * 64];

  for (int t = 0; t < KT2; t += 2) {
#pragma unroll
    for (int f = 0; f < 4; ++f) b2b[f] = w2p[(size_t)((t + 1) * NF2 + f) * 64];
    {
      bf16x8 a2[4];
#pragma unroll
      for (int m = 0; m < 4; ++m) {
        int row = m * 16 + lrow;
        int off = row * 1024 + ((t * 64 + lgrp * 16) ^ ((row & 7) << 4));
        a2[m] = *(const bf16x8*)(h1 + off);
      }
      __builtin_amdgcn_s_setprio(1);
#pragma unroll
      for (int f = 0; f < 4; ++f)
#pragma unroll
        for (int m = 0; m < 4; ++m)
          acc2[m][f] = __builtin_amdgcn_mfma_f32_16x16x32_bf16(a2[m], b2a[f], acc2[m][f], 0, 0, 0);
      __builtin_amdgcn_s_setprio(0);
    }
#pragma unroll
    for (int f = 0; f < 4; ++f) b2a[f] = w2p[(size_t)((t + 2) * NF2 + f) * 64];
    {
      bf16x8 a2[4];
#pragma unroll
      for (int m = 0; m < 4; ++m) {
        int row = m * 16 + lrow;
        int off = row * 1024 + (((t + 1) * 64 + lgrp * 16) ^ ((row & 7) << 4));
        a2[m] = *(const bf16x8*)(h1 + off);
      }
      __builtin_amdgcn_s_setprio(1);
#pragma unroll
      for (int f = 0; f < 4; ++f)
#pragma unroll
        for (int m = 0; m < 4; ++m)
          acc2[m][f] = __builtin_amdgcn_mfma_f32_16x16x32_bf16(a2[m], b2b[f], acc2[m][f], 0, 0, 0);
      __builtin_amdgcn_s_setprio(0);
    }
  }

  __syncthreads();   // all h1 reads done before overwriting with h2

  // epilogue 2 -> h2 in reused LDS (cols >= 200 exact zeros: acc==0, bias==0)
#pragma unroll
  for (int m = 0; m < 4; ++m) {
#pragma unroll
    for (int f = 0; f < 4; ++f) {
      int col = w * 64 + f * 16 + lrow;
      float bias = sb2[col];
#pragma unroll
      for (int r = 0; r < 4; ++r) {
        int row = m * 16 + lgrp * 4 + r;
        float v = fmaxf(acc2[m][f][r] + bias, 0.f);
        int off = row * 512 + ((col * 2) ^ ((row & 7) << 4));
        *(__bf16*)(h1 + off) = (__bf16)v;
      }
    }
  }
  __syncthreads();

  // ---------------- Layer 3: out = h2 @ W3 + b3 (wave w owns rows w*16..) ----------------
  {
    f32x4 a3 = FZ;
    const bf16x8* w3p = (const bf16x8*)w3s + lane;
#pragma unroll
    for (int t = 0; t < KT3; ++t) {
      int row = w * 16 + lrow;
      int off = row * 512 + ((t * 64 + lgrp * 16) ^ ((row & 7) << 4));
      bf16x8 a = *(const bf16x8*)(h1 + off);
      a3 = __builtin_amdgcn_mfma_f32_16x16x32_bf16(a, w3p[(size_t)t * 64], a3, 0, 0, 0);
    }
    if (lrow < 10) {
      float bias = b3[lrow];
#pragma unroll
      for (int r = 0; r < 4; ++r)
        out[(size_t)(brow + w * 16 + lgrp * 4 + r) * 10 + lrow] = a3[r] + bias;
    }
  }
}

extern "C" void kernel_launch(void* const* d_in, const int* in_sizes, int n_in,
                              void* d_out, int out_size, void* d_ws, size_t ws_size,
                              hipStream_t stream) {
  const float* x  = (const float*)d_in[0];
  const float* cw = (const float*)d_in[1];
  const float* W1 = (const float*)d_in[2];
  const float* b1 = (const float*)d_in[3];
  const float* W2 = (const float*)d_in[4];
  const float* b2 = (const float*)d_in[5];
  const float* W3 = (const float*)d_in[6];
  const float* b3 = (const float*)d_in[7];
  float* out = (float*)d_out;

  __bf16* w1s = (__bf16*)d_ws;                      // 800 KB
  __bf16* w2s = w1s + (size_t)KT1 * NF1 * 64 * 8;   // 256 KB
  __bf16* w3s = w2s + (size_t)KT2 * NF2 * 64 * 8;   // 8 KB

  prep_w1<<<200, 256, 0, stream>>>(W1, cw, w1s);
  prep_w2<<<64, 256, 0, stream>>>(W2, w2s);
  prep_w3<<<2, 256, 0, stream>>>(W3, w3s);

  mlp_fused<<<65536 / 64, 256, 0, stream>>>(x, w1s, w2s, w3s, b1, b2, b3, out);
}